// Round 1
// baseline (46.183 us; speedup 1.0000x reference)
//
#include <hip/hip_runtime.h>

// Problem constants (from reference setup_inputs)
#define NB 64      // batch
#define NL 128     // L (rows indexed by edges)
#define NQ 128     // Q
#define NE 16384   // edges

// Workspace float layout
#define WS_WT   0        // [128][128] W^T: WT[j*128+i] = sum of w_e over edges (i,j)
#define WS_AT   16384    // [128][128] A_fid^T: AT[q*128+p] = A_fid[p][q]
#define WS_TW   32768    // total weight
#define WS_NUM  32769    // numerator accumulator (sum_b s_b)
#define WS_END  32770

// ---------------------------------------------------------------------------
// Kernel 1: build A_fid^T, scatter edge weights into W^T, reduce total weight.
// grid = 64 blocks x 256 threads; idx covers exactly 16384 = Q*Q = E.
// ---------------------------------------------------------------------------
__global__ void prep_kernel(const float* __restrict__ dhw,
                            const float* __restrict__ derr,
                            const int* __restrict__ pairs,
                            const float* __restrict__ wts,
                            float* __restrict__ ws) {
    const int idx = blockIdx.x * 256 + threadIdx.x;

    // A_fid (transposed store): AT[q*128+p] = (dhw[p,q]==1) * max(1-derr[p,q],0)
    {
        const float hw = dhw[idx];
        const float er = derr[idx];
        const float a  = (hw == 1.0f) ? fmaxf(1.0f - er, 0.0f) : 0.0f;
        const int p = idx >> 7, q = idx & 127;
        ws[WS_AT + q * 128 + p] = a;
    }

    // Edge scatter: W[i,j] += w  stored transposed as WT[j*128+i]
    const int i = pairs[2 * idx];
    const int j = pairs[2 * idx + 1];
    const float w = wts[idx];
    atomicAdd(&ws[WS_WT + j * 128 + i], w);

    // Block-reduce w into total weight (one atomic per block)
    float s = w;
    #pragma unroll
    for (int off = 32; off; off >>= 1) s += __shfl_down(s, off, 64);
    __shared__ float red[4];
    const int lane = threadIdx.x & 63, wv = threadIdx.x >> 6;
    if (lane == 0) red[wv] = s;
    __syncthreads();
    if (threadIdx.x == 0)
        atomicAdd(&ws[WS_TW], red[0] + red[1] + red[2] + red[3]);
}

// ---------------------------------------------------------------------------
// Kernel 2: per (batch b, 32-row i-tile) compute partial
//   s = sum_{ii,p} P_b[i0+ii][p] * sum_q A[p][q] * (sum_j W[i0+ii][j] P_b[j][q])
// grid = 64*4 = 256 blocks x 256 threads (one block per CU).
// ---------------------------------------------------------------------------
__global__ __launch_bounds__(256) void batch_kernel(const float* __restrict__ P,
                                                    float* __restrict__ ws) {
    const int b  = blockIdx.x >> 2;
    const int i0 = (blockIdx.x & 3) * 32;
    const float* __restrict__ Pb = P + b * (NL * NQ);
    const float* __restrict__ WT = ws + WS_WT;
    const float* __restrict__ AT = ws + WS_AT;

    __shared__ float WT_lds[NL * 32];   // [j][ii]  16 KB
    __shared__ float GT_lds[NQ * 33];   // [q][ii]  padded stride 33 (bank spread)
    __shared__ float red[4];

    const int t = threadIdx.x;

    // Stage W^T tile: WT_lds[j][ii] = W[i0+ii][j]
    #pragma unroll
    for (int k = 0; k < 4; ++k) {
        const int j  = (t >> 3) + k * 32;
        const int ii = (t & 7) * 4;
        *(float4*)&WT_lds[j * 32 + ii] = *(const float4*)&WT[j * 128 + i0 + ii];
    }
    __syncthreads();

    const int c0  = (t & 31) * 4;   // q in phase G, p in phase H (covers 0..127)
    const int ii0 = (t >> 5) * 4;   // 8 groups * 4 = 32 tile rows

    // ---- Phase G: G[ii][q] = sum_j W[i0+ii][j] * Pb[j][q] ----
    float acc[4][4] = {};
    #pragma unroll 4
    for (int j = 0; j < NL; ++j) {
        const float4 wv = *(const float4*)&WT_lds[j * 32 + ii0];      // LDS broadcast
        const float4 pv = *(const float4*)&Pb[j * NQ + c0];           // coalesced L2
        const float wa[4] = {wv.x, wv.y, wv.z, wv.w};
        const float pa[4] = {pv.x, pv.y, pv.z, pv.w};
        #pragma unroll
        for (int a = 0; a < 4; ++a)
            #pragma unroll
            for (int c = 0; c < 4; ++c)
                acc[a][c] += wa[a] * pa[c];
    }
    // Store G transposed: GT_lds[q][ii]
    #pragma unroll
    for (int c = 0; c < 4; ++c)
        #pragma unroll
        for (int a = 0; a < 4; ++a)
            GT_lds[(c0 + c) * 33 + ii0 + a] = acc[a][c];
    __syncthreads();

    // ---- Phase H: H[ii][p] = sum_q G[ii][q] * A[p][q];  s += P[i0+ii][p]*H ----
    float acc2[4][4] = {};
    #pragma unroll 2
    for (int q = 0; q < NQ; ++q) {
        const float4 av = *(const float4*)&AT[q * 128 + c0];          // coalesced L2
        const float aa[4] = {av.x, av.y, av.z, av.w};
        float ga[4];
        #pragma unroll
        for (int a = 0; a < 4; ++a) ga[a] = GT_lds[q * 33 + ii0 + a]; // LDS broadcast
        #pragma unroll
        for (int a = 0; a < 4; ++a)
            #pragma unroll
            for (int c = 0; c < 4; ++c)
                acc2[a][c] += ga[a] * aa[c];
    }

    float s = 0.0f;
    #pragma unroll
    for (int a = 0; a < 4; ++a) {
        const float4 pv = *(const float4*)&Pb[(i0 + ii0 + a) * NQ + c0];
        s += pv.x * acc2[a][0] + pv.y * acc2[a][1] +
             pv.z * acc2[a][2] + pv.w * acc2[a][3];
    }

    // Block reduce, one atomic per block
    #pragma unroll
    for (int off = 32; off; off >>= 1) s += __shfl_down(s, off, 64);
    if ((t & 63) == 0) red[t >> 6] = s;
    __syncthreads();
    if (t == 0) atomicAdd(&ws[WS_NUM], red[0] + red[1] + red[2] + red[3]);
}

// ---------------------------------------------------------------------------
// Kernel 3: loss = -(num / B) / max(total_weight, 1e-8)
// ---------------------------------------------------------------------------
__global__ void finalize_kernel(const float* __restrict__ ws,
                                float* __restrict__ out) {
    const float tw = fmaxf(ws[WS_TW], 1e-8f);
    out[0] = -ws[WS_NUM] / ((float)NB * tw);
}

extern "C" void kernel_launch(void* const* d_in, const int* in_sizes, int n_in,
                              void* d_out, int out_size, void* d_ws, size_t ws_size,
                              hipStream_t stream) {
    const float* P    = (const float*)d_in[0];
    const float* dhw  = (const float*)d_in[1];
    const float* derr = (const float*)d_in[2];
    const int*   prs  = (const int*)d_in[3];
    const float* wts  = (const float*)d_in[4];
    float* ws  = (float*)d_ws;
    float* out = (float*)d_out;

    hipMemsetAsync(ws, 0, WS_END * sizeof(float), stream);
    prep_kernel<<<NE / 256, 256, 0, stream>>>(dhw, derr, prs, wts, ws);
    batch_kernel<<<NB * 4, 256, 0, stream>>>(P, ws);
    finalize_kernel<<<1, 1, 0, stream>>>(ws, out);
}

// Round 2
// 37.054 us; speedup vs baseline: 1.2464x; 1.2464x over previous
//
#include <hip/hip_runtime.h>

// Problem constants (from reference setup_inputs)
#define NB 64      // batch
#define NL 128     // L (rows indexed by edges)
#define NQ 128     // Q
#define NE 16384   // edges

// Workspace float layout
#define WS_WT   0          // [128][128] WT[j*128+i] = W[i][j] (edge-weight scatter)
#define WS_TW   16384      // total weight
#define WS_NUM  16385      // numerator accumulator (sum_b s_b)
#define WS_A    16388      // [128][128] A_fid[p*128+q], 16B-aligned (16388*4 % 16 == 0)
#define WS_END  (WS_A + 16384)

// ---------------------------------------------------------------------------
// Kernel 1: build A_fid (plain layout), scatter edge weights into W^T,
// reduce total weight. grid = 64 x 256; idx covers 16384 = Q*Q = E.
// ---------------------------------------------------------------------------
__global__ void prep_kernel(const float* __restrict__ dhw,
                            const float* __restrict__ derr,
                            const int* __restrict__ pairs,
                            const float* __restrict__ wts,
                            float* __restrict__ ws) {
    const int idx = blockIdx.x * 256 + threadIdx.x;

    // A_fid[p][q] = (dhw[p,q]==1) * max(1-derr[p,q],0), plain store
    {
        const float hw = dhw[idx];
        const float er = derr[idx];
        const float a  = (hw == 1.0f) ? fmaxf(1.0f - er, 0.0f) : 0.0f;
        ws[WS_A + idx] = a;
    }

    // Edge scatter: W[i,j] += w, stored transposed as WT[j*128+i]
    const int i = pairs[2 * idx];
    const int j = pairs[2 * idx + 1];
    const float w = wts[idx];
    atomicAdd(&ws[WS_WT + j * 128 + i], w);

    // Block-reduce w into total weight (one atomic per block)
    float s = w;
    #pragma unroll
    for (int off = 32; off; off >>= 1) s += __shfl_down(s, off, 64);
    __shared__ float red[4];
    const int lane = threadIdx.x & 63, wv = threadIdx.x >> 6;
    if (lane == 0) red[wv] = s;
    __syncthreads();
    if (threadIdx.x == 0)
        atomicAdd(&ws[WS_TW], red[0] + red[1] + red[2] + red[3]);
}

// ---------------------------------------------------------------------------
// Kernel 2: block = (batch b, 32-row i-tile, 32-col q-chunk).
//   G[ii][qq] = sum_j W[i0+ii][j] * Pb[j][q0+qq]          (phase G, 2x2/thread)
//   M[p][qq]  = sum_ii Pb[i0+ii][p] * G[ii][qq]           (phase M, 4x4/thread)
//   s_partial = sum_{p,qq} A[p][q0+qq] * M[p][qq]  -> atomic into WS_NUM
// grid = 64*4*4 = 1024 blocks x 256 threads; LDS 37 KB -> 4 blocks/CU.
// ---------------------------------------------------------------------------
__global__ __launch_bounds__(256, 4) void batch_kernel(const float* __restrict__ P,
                                                       float* __restrict__ ws) {
    const int blk = blockIdx.x;
    const int b   = blk >> 4;
    const int i0  = ((blk >> 2) & 3) * 32;
    const int q0  = (blk & 3) * 32;
    const float* __restrict__ Pb  = P + b * (NL * NQ);
    const float* __restrict__ WTg = ws + WS_WT;
    const float* __restrict__ Ag  = ws + WS_A;

    __shared__ float sm[4096 + 4096 + 1024 + 4];
    float* WT  = sm;          // [j][ii] stride 32 (16 KB); reused as Pi [ii][p] stride 128
    float* Pq  = sm + 4096;   // [j][qq] stride 32 (16 KB)
    float* G   = sm + 8192;   // [ii][qq] stride 32 (4 KB)
    float* red = sm + 9216;

    const int t = threadIdx.x;

    // Stage W tile (transposed to [j][ii]) and P q-slab [j][qq]; 1024 float4 each
    #pragma unroll
    for (int r = 0; r < 4; ++r) {
        const int f = t + 256 * r;
        const int j = f >> 3, c = (f & 7) * 4;
        *(float4*)&WT[j * 32 + c] = *(const float4*)&WTg[j * 128 + i0 + c];
        *(float4*)&Pq[j * 32 + c] = *(const float4*)&Pb[j * 128 + q0 + c];
    }
    __syncthreads();

    // ---- Phase G: 2x2 per thread (16x16 thread grid over 32x32 output) ----
    const int ii0 = (t >> 4) * 2;   // 16 groups * 2 = 32 rows
    const int qq0 = (t & 15) * 2;   // 16 groups * 2 = 32 cols
    float g00 = 0.f, g01 = 0.f, g10 = 0.f, g11 = 0.f;
    #pragma unroll 8
    for (int j = 0; j < NL; ++j) {
        const float2 wv = *(const float2*)&WT[j * 32 + ii0];   // broadcast, conflict-free
        const float2 pv = *(const float2*)&Pq[j * 32 + qq0];   // broadcast, conflict-free
        g00 += wv.x * pv.x; g01 += wv.x * pv.y;
        g10 += wv.y * pv.x; g11 += wv.y * pv.y;
    }
    __syncthreads();   // all WT reads done -> WT region reusable

    // Write G; restage Pi = Pb[i0..i0+31][0..127] over the WT region
    *(float2*)&G[ ii0      * 32 + qq0] = make_float2(g00, g01);
    *(float2*)&G[(ii0 + 1) * 32 + qq0] = make_float2(g10, g11);
    float* Pi = WT;   // [ii][p] stride 128
    #pragma unroll
    for (int r = 0; r < 4; ++r) {
        const int e = (t + 256 * r) * 4;     // flat float idx into 32x128 tile
        *(float4*)&Pi[e] = *(const float4*)&Pb[i0 * NQ + e];   // fully coalesced
    }
    __syncthreads();

    // ---- Phase M: 4x4 per thread (32 p-groups x 8 q-groups) ----
    const int p0  = (t >> 3) * 4;   // 32 groups * 4 = 128 p
    const int qm0 = (t & 7) * 4;    // 8 groups * 4 = 32 qq
    float m00=0,m01=0,m02=0,m03=0, m10=0,m11=0,m12=0,m13=0,
          m20=0,m21=0,m22=0,m23=0, m30=0,m31=0,m32=0,m33=0;
    #pragma unroll 4
    for (int ii = 0; ii < 32; ++ii) {
        const float4 pv = *(const float4*)&Pi[ii * 128 + p0];  // broadcast, conflict-free
        const float4 gv = *(const float4*)&G[ii * 32 + qm0];   // broadcast, conflict-free
        m00 += pv.x * gv.x; m01 += pv.x * gv.y; m02 += pv.x * gv.z; m03 += pv.x * gv.w;
        m10 += pv.y * gv.x; m11 += pv.y * gv.y; m12 += pv.y * gv.z; m13 += pv.y * gv.w;
        m20 += pv.z * gv.x; m21 += pv.z * gv.y; m22 += pv.z * gv.z; m23 += pv.z * gv.w;
        m30 += pv.w * gv.x; m31 += pv.w * gv.y; m32 += pv.w * gv.z; m33 += pv.w * gv.w;
    }

    // Dot with A (each A element read exactly once per block, coalesced-ish, L2-hot)
    float s = 0.f;
    {
        const float4 a0 = *(const float4*)&Ag[(p0 + 0) * 128 + q0 + qm0];
        const float4 a1 = *(const float4*)&Ag[(p0 + 1) * 128 + q0 + qm0];
        const float4 a2 = *(const float4*)&Ag[(p0 + 2) * 128 + q0 + qm0];
        const float4 a3 = *(const float4*)&Ag[(p0 + 3) * 128 + q0 + qm0];
        s += a0.x*m00 + a0.y*m01 + a0.z*m02 + a0.w*m03;
        s += a1.x*m10 + a1.y*m11 + a1.z*m12 + a1.w*m13;
        s += a2.x*m20 + a2.y*m21 + a2.z*m22 + a2.w*m23;
        s += a3.x*m30 + a3.y*m31 + a3.z*m32 + a3.w*m33;
    }

    // Block reduce, one atomic per block
    #pragma unroll
    for (int off = 32; off; off >>= 1) s += __shfl_down(s, off, 64);
    if ((t & 63) == 0) red[t >> 6] = s;
    __syncthreads();
    if (t == 0) atomicAdd(&ws[WS_NUM], red[0] + red[1] + red[2] + red[3]);
}

// ---------------------------------------------------------------------------
// Kernel 3: loss = -(num / B) / max(total_weight, 1e-8)
// ---------------------------------------------------------------------------
__global__ void finalize_kernel(const float* __restrict__ ws,
                                float* __restrict__ out) {
    const float tw = fmaxf(ws[WS_TW], 1e-8f);
    out[0] = -ws[WS_NUM] / ((float)NB * tw);
}

extern "C" void kernel_launch(void* const* d_in, const int* in_sizes, int n_in,
                              void* d_out, int out_size, void* d_ws, size_t ws_size,
                              hipStream_t stream) {
    const float* P    = (const float*)d_in[0];
    const float* dhw  = (const float*)d_in[1];
    const float* derr = (const float*)d_in[2];
    const int*   prs  = (const int*)d_in[3];
    const float* wts  = (const float*)d_in[4];
    float* ws  = (float*)d_ws;
    float* out = (float*)d_out;

    // Zero only what needs zeroing: WT scatter table + TW/NUM scalars.
    hipMemsetAsync(ws, 0, (WS_NUM + 1) * sizeof(float), stream);
    prep_kernel<<<NE / 256, 256, 0, stream>>>(dhw, derr, prs, wts, ws);
    batch_kernel<<<NB * 16, 256, 0, stream>>>(P, ws);
    finalize_kernel<<<1, 1, 0, stream>>>(ws, out);
}